// Round 9
// baseline (59.777 us; speedup 1.0000x reference)
//
#include <hip/hip_runtime.h>
#include <cstdint>

#define NCOARSE 4000
#define NFINE   40000
#define DIM     128
#define GRES    8
#define CELLH   0.125f
#define CAP_C   40       // coarse slots per cell (lambda=7.8, 11 sigma)
#define CAP_F   160      // fine slots per cell (lambda=78.1, 9 sigma)
#define PPB     16       // fine points per k_main block
#define CHUNKS  10       // CAP_F / PPB
#define SCAP    640      // staged-candidate cap (float4)
#define NS      172      // scatter blocks in k_build (ceil(44000/256))
#define NYG     125      // Y-GEMM blocks (4000 rows / 32)

__device__ __forceinline__ uint64_t min64(uint64_t a, uint64_t b) { return a < b ? a : b; }
__device__ __forceinline__ uint64_t max64(uint64_t a, uint64_t b) { return a > b ? a : b; }
__device__ __forceinline__ int cell_coord(float x) {
    int c = (int)(x * 8.0f);
    return c < 0 ? 0 : (c > 7 ? 7 : c);
}

// ---------------- zero the two 512-int counter arrays ----------------
__global__ __launch_bounds__(256) void k_zero(int* __restrict__ p) {
    p[blockIdx.x * 256 + threadIdx.x] = 0;
}

// ---------------- build: direct-slot scatter + Y = xc @ W ----------------
__global__ __launch_bounds__(256) void k_build(const float* __restrict__ pc,
                                               const float* __restrict__ pf,
                                               const float* __restrict__ xc,
                                               const float* __restrict__ W,
                                               int* __restrict__ cntC, int* __restrict__ cntF,
                                               float4* __restrict__ ptsC, float4* __restrict__ srtF,
                                               float* __restrict__ Y) {
    __shared__ float xs[32][DIM];    // 16 KB (used by GEMM branch only)
    const int bid = blockIdx.x, tid = threadIdx.x;
    if (bid < NS) {
        const int i = bid * 256 + tid;
        if (i < NCOARSE) {
            const float x = pc[3*i], y = pc[3*i+1], z = pc[3*i+2];
            const int c = (cell_coord(z) << 6) | (cell_coord(y) << 3) | cell_coord(x);
            const int slot = atomicAdd(&cntC[c], 1);
            if (slot < CAP_C) ptsC[c * CAP_C + slot] = make_float4(x, y, z, __int_as_float(i));
        } else if (i < NCOARSE + NFINE) {
            const int j = i - NCOARSE;
            const float x = pf[3*j], y = pf[3*j+1], z = pf[3*j+2];
            const int c = (cell_coord(z) << 6) | (cell_coord(y) << 3) | cell_coord(x);
            const int slot = atomicAdd(&cntF[c], 1);
            if (slot < CAP_F) srtF[c * CAP_F + slot] = make_float4(x, y, z, __int_as_float(j));
        }
    } else {
        // Y-GEMM tile: 32 rows x 128 cols; thread=(rq,jq) does rows rq+8i, cols jq*4..+3
        const int g  = bid - NS;
        const int r0 = g * 32;
        #pragma unroll
        for (int t = 0; t < 4; ++t)
            reinterpret_cast<float4*>(xs)[tid + t * 256] =
                reinterpret_cast<const float4*>(xc + r0 * DIM)[tid + t * 256];
        __syncthreads();
        const int rq = tid >> 5;       // 0..7
        const int jq = tid & 31;       // col quad
        float acc[4][4];
        #pragma unroll
        for (int i = 0; i < 4; ++i)
            #pragma unroll
            for (int j = 0; j < 4; ++j) acc[i][j] = 0.f;
        #pragma unroll 2
        for (int k = 0; k < DIM; ++k) {
            const float4 wv = *reinterpret_cast<const float4*>(W + k * DIM + jq * 4);
            #pragma unroll
            for (int i = 0; i < 4; ++i) {
                const float a = xs[rq + 8 * i][k];
                acc[i][0] += a * wv.x; acc[i][1] += a * wv.y;
                acc[i][2] += a * wv.z; acc[i][3] += a * wv.w;
            }
        }
        #pragma unroll
        for (int i = 0; i < 4; ++i)
            *reinterpret_cast<float4*>(Y + (r0 + rq + 8 * i) * DIM + jq * 4) =
                make_float4(acc[i][0], acc[i][1], acc[i][2], acc[i][3]);
    }
}

// ---------------- main: KNN + gather-mean of Y ----------------
// exact top-7 of the union of the 8 octet lanes' sorted 7-lists via 7-round pop-min.
// keys are unique -> exactly one winning lane per round.
__device__ __forceinline__ void popmin_merge(const uint64_t own[7], uint64_t mg[7]) {
    uint64_t a0 = own[0], a1 = own[1], a2 = own[2], a3 = own[3],
             a4 = own[4], a5 = own[5], a6 = own[6];
    #pragma unroll
    for (int r = 0; r < 7; ++r) {
        uint64_t m = a0;
        m = min64(m, __shfl_xor((unsigned long long)m, 1));
        m = min64(m, __shfl_xor((unsigned long long)m, 2));
        m = min64(m, __shfl_xor((unsigned long long)m, 4));
        mg[r] = m;
        const bool win = (a0 == m);
        a0 = win ? a1 : a0;
        a1 = win ? a2 : a1;
        a2 = win ? a3 : a2;
        a3 = win ? a4 : a3;
        a4 = win ? a5 : a4;
        a5 = win ? a6 : a5;
        a6 = win ? ~0ull : a6;
    }
}

__device__ __forceinline__ bool done_check(uint64_t k7, float fx, float fy, float fz,
                                           int ix, int iy, int iz, int s) {
    const float d7 = __uint_as_float((uint32_t)(k7 >> 32));
    float clear = 1e30f;
    if (ix - s >= 0) clear = fminf(clear, __fsub_rn(fx, (float)(ix - s) * CELLH));
    if (ix + s <= 6) clear = fminf(clear, __fsub_rn((float)(ix + s + 1) * CELLH, fx));
    if (iy - s >= 0) clear = fminf(clear, __fsub_rn(fy, (float)(iy - s) * CELLH));
    if (iy + s <= 6) clear = fminf(clear, __fsub_rn((float)(iy + s + 1) * CELLH, fy));
    if (iz - s >= 0) clear = fminf(clear, __fsub_rn(fz, (float)(iz - s) * CELLH));
    if (iz + s <= 6) clear = fminf(clear, __fsub_rn((float)(iz + s + 1) * CELLH, fz));
    return d7 < clear * clear * 0.9999f;   // NaN sentinel -> false
}

#define INS(p) { \
    const float ddx = __fsub_rn(fx, (p).x); \
    const float ddy = __fsub_rn(fy, (p).y); \
    const float ddz = __fsub_rn(fz, (p).z); \
    const float d2  = __fadd_rn(__fadd_rn(__fmul_rn(ddx, ddx), __fmul_rn(ddy, ddy)), \
                                __fmul_rn(ddz, ddz)); \
    const uint64_t v = ((uint64_t)__float_as_uint(d2) << 32) | (uint32_t)__float_as_uint((p).w); \
    if (v < own[6]) { \
        own[6] = min64(own[6], max64(own[5], v)); \
        own[5] = min64(own[5], max64(own[4], v)); \
        own[4] = min64(own[4], max64(own[3], v)); \
        own[3] = min64(own[3], max64(own[2], v)); \
        own[2] = min64(own[2], max64(own[1], v)); \
        own[1] = min64(own[1], max64(own[0], v)); \
        own[0] = min64(own[0], v); \
    } }

__global__ __launch_bounds__(128) void k_main(
    const float*  __restrict__ Y,        // [4000][128] = xc @ W
    const float*  __restrict__ bias,
    const int*    __restrict__ cntC,
    const int*    __restrict__ cntF,
    const float4* __restrict__ ptsG,     // fixed-slot coarse
    const float4* __restrict__ srtF,     // fixed-slot fine
    float* __restrict__ out)
{
    __shared__ float4 spts[SCAP];
    __shared__ int rBeg[32], rLds[32];
    __shared__ int idx6[PPB][6];
    __shared__ int forig[PPB];
    __shared__ int metaT[1];

    const int bid  = blockIdx.x;
    const int tid  = threadIdx.x;
    const int cell = bid & 511;
    const int chunk= bid >> 9;

    const int ctot = min(cntF[cell], CAP_F);
    const int base = chunk * PPB;
    const int npts = min(PPB, ctot - base);
    if (npts <= 0) return;                      // block-uniform

    const int fl  = tid >> 3;        // 0..15 local fine point
    const int par = tid & 7;         // lane within point-octet
    const int ix = cell & 7, iy = (cell >> 3) & 7, iz = cell >> 6;

    const int srcf = min(fl, npts - 1);
    const float4 fp = srtF[cell * CAP_F + base + srcf];
    const float fx = fp.x, fy = fp.y, fz = fp.z;
    if (par == 0) forig[fl] = (fl < npts) ? __float_as_int(fp.w) : -1;

    const int bx0 = max(ix - 1, 0), bx1 = min(ix + 1, 7);
    const int by0 = max(iy - 1, 0), by1 = min(iy + 1, 7);
    const int bz0 = max(iz - 1, 0), bz1 = min(iz + 1, 7);
    const int nx = bx1 - bx0 + 1, ny = by1 - by0 + 1, nz = bz1 - bz0 + 1;
    const int ncell = nx * ny * nz;             // <= 27

    // neighborhood table + prefix (first wave, lanes 0..31)
    if (tid < 32) {
        const bool valid = tid < ncell;
        int len = 0, bg = 0;
        if (valid) {
            const int ex = bx0 + tid % nx;
            const int rem = tid / nx;
            const int ey = by0 + rem % ny;
            const int ez = bz0 + rem / ny;
            const int cc = (ez << 6) | (ey << 3) | ex;
            len = min(cntC[cc], CAP_C);
            bg  = cc * CAP_C;
        }
        int x = len;
        #pragma unroll
        for (int o = 1; o < 32; o <<= 1) {
            const int v = __shfl_up(x, o);
            if (tid >= o) x += v;
        }
        rBeg[tid] = valid ? bg : 0;
        rLds[tid] = valid ? (x - len) : 0x7fffffff;
        if (tid == ncell - 1) metaT[0] = x;
    }
    __syncthreads();

    const int total  = metaT[0];
    const bool staged = (total <= SCAP);
    if (staged) {
        for (int g = tid; g < total; g += 128) {
            int lo = 0, hi = 31;
            while (lo < hi) { const int mid = (lo + hi + 1) >> 1; if (rLds[mid] <= g) lo = mid; else hi = mid - 1; }
            spts[g] = ptsG[rBeg[lo] + (g - rLds[lo])];
        }
    }
    __syncthreads();

    uint64_t own[7];
    #pragma unroll
    for (int r = 0; r < 7; ++r) own[r] = ~0ull;

    if (staged) {
        #pragma unroll 4
        for (int i = par; i < total; i += 8) { float4 p = spts[i]; INS(p) }
    } else {
        for (int cz = bz0; cz <= bz1; ++cz)
            for (int cy = by0; cy <= by1; ++cy)
                for (int cx = bx0; cx <= bx1; ++cx) {
                    const int cc = (cz << 6) | (cy << 3) | cx;
                    const int len = min(cntC[cc], CAP_C);
                    const int bg  = cc * CAP_C;
                    for (int i = par; i < len; i += 8) { float4 p = ptsG[bg + i]; INS(p) }
                }
    }

    uint64_t mg[7];
    popmin_merge(own, mg);
    bool done = done_check(mg[6], fx, fy, fz, ix, iy, iz, 1);

    for (int s = 2; s <= 7; ++s) {
        if (__all(done)) break;
        if (!done) {
            for (int dz = -s; dz <= s; ++dz) {
                const int cz = iz + dz;
                if ((unsigned)cz >= (unsigned)GRES) continue;
                const bool fz_face = (dz == -s) | (dz == s);
                for (int dy = -s; dy <= s; ++dy) {
                    const int cy = iy + dy;
                    if ((unsigned)cy >= (unsigned)GRES) continue;
                    const bool yz_face = fz_face | (dy == -s) | (dy == s);
                    for (int dx = -s; dx <= s; ++dx) {
                        if (!yz_face && dx > -s && dx < s) continue;
                        const int cx = ix + dx;
                        if ((unsigned)cx >= (unsigned)GRES) continue;
                        if (cx >= bx0 && cx <= bx1 && cy >= by0 && cy <= by1 &&
                            cz >= bz0 && cz <= bz1) continue;   // already scanned
                        const int cc = (cz << 6) | (cy << 3) | cx;
                        const int len = min(cntC[cc], CAP_C);
                        const int bg  = cc * CAP_C;
                        for (int i = par; i < len; i += 8) { float4 p = ptsG[bg + i]; INS(p) }
                    }
                }
            }
            popmin_merge(own, mg);
            done = done_check(mg[6], fx, fy, fz, ix, iy, iz, s);
        }
    }

    if (par == 0) {
        // 6th/7th sqrt tie repair (reference sorts by f32 sqrt, stable)
        int i5 = (int)(uint32_t)mg[5];
        const int i6 = (int)(uint32_t)mg[6];
        const float d5 = sqrtf(__uint_as_float((uint32_t)(mg[5] >> 32)));
        const float d6 = sqrtf(__uint_as_float((uint32_t)(mg[6] >> 32)));
        if (d5 == d6 && i6 < i5) i5 = i6;
        idx6[fl][0] = (int)(uint32_t)mg[0];
        idx6[fl][1] = (int)(uint32_t)mg[1];
        idx6[fl][2] = (int)(uint32_t)mg[2];
        idx6[fl][3] = (int)(uint32_t)mg[3];
        idx6[fl][4] = (int)(uint32_t)mg[4];
        idx6[fl][5] = i5;
    }
    __syncthreads();

    // ---- epilogue: out[f] = mean(Y[idx6]) + b ; lane par covers 16 dims
    {
        const int fr = forig[fl];
        if (fr >= 0) {
            const int id0 = idx6[fl][0], id1 = idx6[fl][1], id2 = idx6[fl][2];
            const int id3 = idx6[fl][3], id4 = idx6[fl][4], id5 = idx6[fl][5];
            constexpr float inv6 = 1.0f / 6.0f;
            #pragma unroll
            for (int k = 0; k < 4; ++k) {
                const int q = (k * 8 + par) * 4;     // float offset, contiguous across par
                const float4 y0 = *reinterpret_cast<const float4*>(Y + id0 * DIM + q);
                const float4 y1 = *reinterpret_cast<const float4*>(Y + id1 * DIM + q);
                const float4 y2 = *reinterpret_cast<const float4*>(Y + id2 * DIM + q);
                const float4 y3 = *reinterpret_cast<const float4*>(Y + id3 * DIM + q);
                const float4 y4 = *reinterpret_cast<const float4*>(Y + id4 * DIM + q);
                const float4 y5 = *reinterpret_cast<const float4*>(Y + id5 * DIM + q);
                const float4 bv = *reinterpret_cast<const float4*>(bias + q);
                float4 o;
                o.x = (y0.x + y1.x + y2.x + y3.x + y4.x + y5.x) * inv6 + bv.x;
                o.y = (y0.y + y1.y + y2.y + y3.y + y4.y + y5.y) * inv6 + bv.y;
                o.z = (y0.z + y1.z + y2.z + y3.z + y4.z + y5.z) * inv6 + bv.z;
                o.w = (y0.w + y1.w + y2.w + y3.w + y4.w + y5.w) * inv6 + bv.w;
                *reinterpret_cast<float4*>(out + fr * DIM + q) = o;
            }
        }
    }
}

extern "C" void kernel_launch(void* const* d_in, const int* in_sizes, int n_in,
                              void* d_out, int out_size, void* d_ws, size_t ws_size,
                              hipStream_t stream) {
    const float* xc = (const float*)d_in[0];
    const float* pc = (const float*)d_in[1];
    const float* pf = (const float*)d_in[2];
    const float* W  = (const float*)d_in[3];
    const float* b  = (const float*)d_in[4];
    float* out = (float*)d_out;

    // ws layout (bytes):
    //   0        cntC   512 ints (2048)
    //   2048     cntF   512 ints (2048)
    //   4096     ptsC   512*40 float4  (327680)
    //   331776   srtF   512*160 float4 (1310720)
    //   1642496  Y      4000*128 f32   (2048000)   total 3690496
    int*    cntC = (int*)d_ws;
    int*    cntF = (int*)((char*)d_ws + 2048);
    float4* ptsC = (float4*)((char*)d_ws + 4096);
    float4* srtF = (float4*)((char*)d_ws + 331776);
    float*  Y    = (float*)((char*)d_ws + 1642496);

    k_zero <<<dim3(4),            dim3(256), 0, stream>>>((int*)d_ws);   // zero cntC + cntF
    k_build<<<dim3(NS + NYG),     dim3(256), 0, stream>>>(pc, pf, xc, W, cntC, cntF, ptsC, srtF, Y);
    k_main <<<dim3(512 * CHUNKS), dim3(128), 0, stream>>>(Y, b, cntC, cntF, ptsC, srtF, out);
}